// Round 20
// baseline (32.669 us; speedup 1.0000x reference)
//
#include <hip/hip_runtime.h>

// CTC batch cost (Keras ctc_batch_cost), B=256, T=512, C=128, L=64.
// 256 blocks x 192 threads: wave0 = consumer, waves1-2 = half-producers.
// FUSED 2-STEP recurrence: the serial cross-lane cost is paid once per 2
// steps, via 3 PARALLEL ops (dpp A1, dpp A0, bpermute lane-2 A1):
//   A1'' = u1*A1 + u2*A0 + sc0*(u3*DA1 + u4*DA0) + scd*u5*D2A1
//   A0'' = 0.25*A0 + sc0*(v2*DA1 + v3*DA0) + scd*v4*D2A1
//   A2'' = 0.25*A2 + 0.25*A1 + 0.5*A1mid          (HAS128 only)
// u/v coeffs = products of q's (q=0.5*(pl+eps)/(pb+eps)), neighbor q (Dq1)
// and skip flags — precomputed by producers. sc0=2^(e[l-1]-e l), scd=2^(e[l-2]-e l)
// (masked 0 for lanes<2); per-lane pow2 exponent e; trigger renorm every 2
// windows (wave-vote, rare). Chunks cover rows 32c+1..32c+32 so windows never
// straddle buffers; last chunk's row-512 load is exec-masked (no OOB).

#define B_ 256
#define T_ 512
#define C_ 128
#define L_ 64
#define BLANK_ 127
#define EPSF (1e-7f)
#define NW 16              // windows (2 steps each) per chunk
#define LSTR 148           // per-lane coeff stride (dwords), 16B-aligned
#define LN2F 0.6931471805599453f

#define EXP2(x) __builtin_amdgcn_exp2f(x)   // v_exp_f32 (base-2)
#define LOG2(x) __builtin_amdgcn_logf(x)    // v_log_f32 (base-2)

__device__ __forceinline__ float lse2_2(float a, float b) {
    float m = fmaxf(a, b);
    float d = fminf(a, b) - m;
    return m + LOG2(1.0f + EXP2(d));
}
__device__ __forceinline__ float dppf(float x) {  // lane i <- i-1; lane0 <- 0
    return __int_as_float(__builtin_amdgcn_update_dpp(
        0, __float_as_int(x), 0x138, 0xf, 0xf, false));
}
__device__ __forceinline__ int dppi(int x) {
    return __builtin_amdgcn_update_dpp(0, x, 0x138, 0xf, 0xf, false);
}
__device__ __forceinline__ float rdlanef(float x, int i) {
    return __int_as_float(__builtin_amdgcn_readlane(__float_as_int(x), i));
}

// ---- producer: stage rows [32c+1+ho, +16) ; exec-mask the OOB row-512 load
__device__ __forceinline__ void stage_half(const float* __restrict__ Pg,
        float (*raw)[32 * C_], int c, int pi, int lane) {
    const int ho = pi * 16;
    const float* src = Pg + (size_t)(32 * c + 1 + ho) * C_;
    float* dst = &raw[c % 3][ho * C_];
    const bool clip = (c == 15) && (pi == 1);
#pragma unroll
    for (int i = 0; i < 8; ++i) {
        if (clip && i == 7) {
            if (lane < 32)
                __builtin_amdgcn_global_load_lds(
                    (const __attribute__((address_space(1))) void*)(src + i * 256 + lane * 4),
                    (__attribute__((address_space(3))) void*)(dst + i * 256), 16, 0, 0);
        } else {
            __builtin_amdgcn_global_load_lds(
                (const __attribute__((address_space(1))) void*)(src + i * 256 + lane * 4),
                (__attribute__((address_space(3))) void*)(dst + i * 256), 16, 0, 0);
        }
    }
}

// ---- producer: coeffs for 8 windows (rows ho..ho+15) of chunk jp
__device__ __forceinline__ void produce_half(const float* __restrict__ rk,
        float* __restrict__ qd, int lane, int label, int lblm,
        float kf, float Dkf, int ho, int t0, int tend, float& llg)
{
    const int r = ho + (lane & 15);
    const float pbv = rk[r * C_ + BLANK_] + EPSF;
    const float rb  = __builtin_amdgcn_rcpf(pbv) * 0.5f;   // 0.5 = decay
    const float erb = EPSF * rb;
    const int t = t0 + r;
    llg += ((lane < 16) && (t < tend)) ? LOG2(pbv) : 0.0f;
    float* base = qd + lane * LSTR;
#pragma unroll
    for (int wl = 0; wl < 8; ++wl) {
        const int r1 = ho + 2 * wl, r2 = r1 + 1;
        const int W = (ho >> 1) + wl;
        const float pl1 = rk[r1 * C_ + label];
        const float pl2 = rk[r2 * C_ + label];
        const float plm = rk[r1 * C_ + lblm];              // lane-1's label
        const float rb1 = rdlanef(rb, 2 * wl),  erb1 = rdlanef(erb, 2 * wl);
        const float rb2 = rdlanef(rb, 2 * wl + 1), erb2 = rdlanef(erb, 2 * wl + 1);
        const float q1  = fmaf(pl1, rb1, erb1);
        const float q2  = fmaf(pl2, rb2, erb2);
        const float Dq1 = fmaf(plm, rb1, erb1);
        const float u1 = q2 * q1;
        const float u2 = fmaf(0.5f, q2, u1);               // q2*(q1+0.5)
        const float u3 = q2 * fmaf(kf, q1 + Dq1, 0.5f);
        const float kd = kf * Dq1;
        const float u4 = q2 * kd;
        const float u5 = u4 * Dkf;
        const float v2 = fmaf(0.5f, Dq1, 0.25f);
        const float v3 = 0.5f * Dq1;
        const float v4 = v3 * Dkf;
        *reinterpret_cast<float4*>(base + 4 * W)      = make_float4(u1, u2, u3, u4);
        *reinterpret_cast<float4*>(base + 64 + 4 * W) = make_float4(u5, v2, v3, v4);
        base[128 + W] = q1;
    }
}

template<bool HAS128>
__device__ __forceinline__ void maybe_renorm2(float& A0, float& A1, float& A2,
        int& e, float& sc0, float& scdm, float& kq, float kf, int bpaddr, int lane)
{
    float m2 = fmaxf(A0, A1);
    if (HAS128) m2 = fmaxf(m2, A2);
    const bool out = (m2 > 16777216.0f) ||
                     ((m2 < 5.9604644775390625e-8f) && (m2 > 0.0f));  // 2^+-24
    if (__any(out)) {
        const float mm = (m2 == 0.0f) ? 1.0f : m2;
        const int eb = __float_as_int(mm) >> 23;
        const float s = __int_as_float((254 - eb) << 23);  // exact 2^(127-eb)
        A0 *= s; A1 *= s;
        if (HAS128) A2 *= s;
        e += eb - 127;
        const int ep = dppi(e);
        int d1 = ep - e;
        d1 = d1 < -126 ? -126 : (d1 > 126 ? 126 : d1);
        sc0 = __int_as_float((d1 + 127) << 23);
        const int e2 = __builtin_amdgcn_ds_bpermute(bpaddr, e);
        int d2 = e2 - e;
        d2 = d2 < -126 ? -126 : (d2 > 126 ? 126 : d2);
        const float scd = __int_as_float((d2 + 127) << 23);
        scdm = (lane >= 2) ? scd : 0.0f;
        kq = kf * sc0;
    }
}

template<bool HAS128, bool FULL>
__device__ __forceinline__ void run_chunk(const float* __restrict__ cb,
        int lane, int rem, int bpaddr, float kf,
        float& A0, float& A1, float& A2, int& e,
        float& sc0, float& scdm, float& kq)
{
    const float* qb = cb + lane * LSTR;
    float4 U[NW], V[NW], Q[4];
#pragma unroll
    for (int k = 0; k < NW; ++k) U[k] = *reinterpret_cast<const float4*>(qb + 4 * k);
#pragma unroll
    for (int k = 0; k < NW; ++k) V[k] = *reinterpret_cast<const float4*>(qb + 64 + 4 * k);
#pragma unroll
    for (int k = 0; k < 4; ++k)  Q[k] = *reinterpret_cast<const float4*>(qb + 128 + 4 * k);
    __builtin_amdgcn_sched_barrier(0);

#pragma unroll
    for (int w = 0; w < NW; ++w) {
        const float s1 = dppf(A1);                      // D1 A1  (VALU pipe)
        const float s0 = dppf(A0);                      // D1 A0  (VALU pipe)
        const float s2 = __int_as_float(
            __builtin_amdgcn_ds_bpermute(bpaddr, __float_as_int(A1)));  // D2 A1
        const float YA = A1 + A0;
        float x  = fmaf(U[w].y, A0, U[w].x * A1);
        float xc = fmaf(U[w].w, s0, U[w].z * s1);
        float y  = fmaf(V[w].z, s0, V[w].y * s1);
        float A1n = fmaf(sc0, xc, x);
        A1n = fmaf(scdm, V[w].x * s2, A1n);
        float A0n = fmaf(sc0, y, 0.25f * A0);
        A0n = fmaf(scdm, V[w].w * s2, A0n);
        float mid = 0.0f;
        if (HAS128 || !FULL) {
            const float q1 = (w & 3) == 0 ? Q[w >> 2].x : (w & 3) == 1 ? Q[w >> 2].y
                           : (w & 3) == 2 ? Q[w >> 2].z : Q[w >> 2].w;
            mid = q1 * fmaf(kq, s1, YA);                // A1 after first step
        }
        const float A2n = HAS128
            ? fmaf(0.25f, A2, fmaf(0.5f, mid, 0.25f * A1)) : A2;
        if (FULL) {
            A0 = A0n; A1 = A1n;
            if (HAS128) A2 = A2n;
        } else {
            const bool fw = (2 * w + 2 <= rem);          // wave-uniform
            const bool hw = (2 * w + 1 == rem);
            const float t1 = sc0 * s1;                   // single-step cands
            const float A0h = fmaf(0.5f, A0, 0.5f * t1);
            const float A1h = mid;
            const float A2h = HAS128 ? fmaf(0.5f, A2, 0.5f * A1) : A2;
            A0 = fw ? A0n : (hw ? A0h : A0);
            A1 = fw ? A1n : (hw ? A1h : A1);
            if (HAS128) A2 = fw ? A2n : (hw ? A2h : A2);
        }
        if ((w & 1) == 1)
            maybe_renorm2<HAS128>(A0, A1, A2, e, sc0, scdm, kq, kf, bpaddr, lane);
    }
}

template<bool HAS128>
__device__ __forceinline__ void consumer_run(const float (*coef)[64 * LSTR],
        const float* extra, int lane, int lab, int tend, int nI, float kf,
        float A0, float A1, int bpaddr, float* out, int b)
{
    float A2 = 0.0f;
    float sc0 = 1.0f, scdm = (lane >= 2) ? 1.0f : 0.0f, kq = kf;
    int e = 0;
    for (int c = 0; c < nI; ++c) {
        const int rem = tend - 1 - 32 * c;
        if (rem >= 32)
            run_chunk<HAS128, true >(&coef[c & 1][0], lane, rem, bpaddr, kf,
                                     A0, A1, A2, e, sc0, scdm, kq);
        else
            run_chunk<HAS128, false>(&coef[c & 1][0], lane, rem, bpaddr, kf,
                                     A0, A1, A2, e, sc0, scdm, kq);
        __builtin_amdgcn_s_barrier();                  // end of interval c
    }
    __builtin_amdgcn_s_barrier();                      // BF: lg halves ready
    const float lg = extra[2] + extra[3];
    const float ef = (float)e + lg + (float)(tend - 1);   // decay accounting
    const float l0 = LOG2(A0) + ef;
    const float l1 = LOG2(A1) + ef;
    const float a_prev = __shfl(l1, lab - 1);             // state 2*lab-1
    float a_last;
    if (HAS128) {
        const float l2 = LOG2(A2) + ef;
        a_last = __shfl(l2, 63);                          // state 128
    } else {
        a_last = __shfl(l0, lab);                         // state 2*lab
    }
    if (lane == 0) out[b] = -LN2F * lse2_2(a_last, a_prev);
}

__global__ __launch_bounds__(192) void ctc_fwd_kernel(
    const int* __restrict__ y_true, const float* __restrict__ y_pred,
    const int* __restrict__ input_len, const int* __restrict__ label_len,
    float* __restrict__ out)
{
    __shared__ __align__(16) float raw[3][32 * C_];        // 48 KB
    __shared__ __align__(16) float coef[2][64 * LSTR];     // 74 KB
    __shared__ float extra[4];                             // [2],[3] = llg halves

    const int b = blockIdx.x;
    const int tid = threadIdx.x;
    const int lane = tid & 63;
    const int wid = tid >> 6;                              // 0=consumer, 1..2
    const float* __restrict__ Pg = y_pred + (size_t)b * T_ * C_;
    const int label = y_true[b * L_ + lane];
    const int in_len = input_len[b];
    const int tend = in_len < T_ ? in_len : T_;            // >= 256
    const int nI = (tend - 1 + 31) / 32;                   // 8..16 chunk intervals

    const int lprev = __shfl_up(label, 1);
    const float kf = (lane > 0 && label != lprev) ? 1.0f : 0.0f;

    if (wid > 0) {
        // --------------- producer half (pi=0: rows 0-15, pi=1: 16-31) --------
        const int pi = wid - 1, ho = pi * 16;
        const float Dkf0 = __shfl_up(kf, 1);
        const float Dkf = (lane >= 1) ? Dkf0 : 0.0f;
        float llg = 0.0f;
        stage_half(Pg, raw, 0, pi, lane);
        stage_half(Pg, raw, 1, pi, lane);
        stage_half(Pg, raw, 2, pi, lane);
        asm volatile("s_waitcnt vmcnt(16)" ::: "memory");  // chunk0 half landed
        produce_half(&raw[0][0], &coef[0][0], lane, label, lprev,
                     kf, Dkf, ho, 1, tend, llg);
        asm volatile("s_waitcnt lgkmcnt(0)" ::: "memory");
        __builtin_amdgcn_s_barrier();                      // B0
        for (int i = 0; i < nI; ++i) {
            const int js = i + 3;
            if (js < 16) stage_half(Pg, raw, js, pi, lane);
            const int jp = i + 1;
            if (jp < nI) {
                const int smax = js < 16 ? js : 15;
                const int N = (smax - jp) * 8;
                if (N >= 16)     asm volatile("s_waitcnt vmcnt(16)" ::: "memory");
                else if (N >= 8) asm volatile("s_waitcnt vmcnt(8)" ::: "memory");
                else             asm volatile("s_waitcnt vmcnt(0)" ::: "memory");
                produce_half(&raw[jp % 3][0], &coef[jp & 1][0], lane, label, lprev,
                             kf, Dkf, ho, 32 * jp + 1, tend, llg);
                asm volatile("s_waitcnt lgkmcnt(0)" ::: "memory");
            }
            __builtin_amdgcn_s_barrier();                  // end of interval i
        }
#pragma unroll
        for (int off = 8; off >= 1; off >>= 1) llg += __shfl_xor(llg, off);
        if (lane == 0) extra[2 + pi] = llg;                // my half's lg
        asm volatile("s_waitcnt lgkmcnt(0)" ::: "memory");
        __builtin_amdgcn_s_barrier();                      // BF
    } else {
        // ------------------------- consumer (wave 0) -------------------------
        const int lab = label_len[b];
        const int bpaddr = ((lane - 2) & 63) * 4;
        float A0 = 0.0f, A1 = 0.0f;
        if (lane == 0) {                                   // t=0 init (row 0)
            A0 = Pg[BLANK_] + EPSF;
            A1 = Pg[label] + EPSF;
        }
        __builtin_amdgcn_s_barrier();                      // B0
        if (lab == L_)
            consumer_run<true >(coef, extra, lane, lab, tend, nI, kf,
                                A0, A1, bpaddr, out, b);
        else
            consumer_run<false>(coef, extra, lane, lab, tend, nI, kf,
                                A0, A1, bpaddr, out, b);
    }
}

extern "C" void kernel_launch(void* const* d_in, const int* in_sizes, int n_in,
                              void* d_out, int out_size, void* d_ws, size_t ws_size,
                              hipStream_t stream) {
    const int*   y_true    = (const int*)d_in[0];
    const float* y_pred    = (const float*)d_in[1];
    const int*   input_len = (const int*)d_in[2];
    const int*   label_len = (const int*)d_in[3];
    float* out = (float*)d_out;

    ctc_fwd_kernel<<<B_, 192, 0, stream>>>(y_true, y_pred, input_len, label_len, out);
}

// Round 21
// 24.167 us; speedup vs baseline: 1.3518x; 1.3518x over previous
//
#include <hip/hip_runtime.h>

// CTC batch cost (Keras ctc_batch_cost), B=256, T=512, C=128, L=64.
// FORWARD-BACKWARD SPLIT: loss = -log sum_s alpha_m(s)*beta_m(s) (invariant).
// 256 blocks x 256 threads: w0 = fwd consumer (t=1..m), w1 = bwd consumer
// (t=tend-1..m+1), w2 = fwd producer, w3 = bwd producer. Serial length per
// chain halves (max 256 steps). Both chains: blank-normalized linear domain,
// 0.5/step decay folded into q, per-lane pow2 exponent, trigger renorm.
// Merge: per-lane log2(alpha*beta) + wave lse-reduce.

#define B_ 256
#define T_ 512
#define C_ 128
#define L_ 64
#define BLANK_ 127
#define EPSF (1e-7f)
#define CHUNK 32
#define QSTRF 36           // fwd q stride (dwords)
#define QSTRB 68           // bwd: q[0..31], ksh[32..63]; 272B, 16B-aligned
#define LN2F 0.6931471805599453f
#define NEGF (-1e30f)

#define EXP2(x) __builtin_amdgcn_exp2f(x)   // v_exp_f32 (base-2)
#define LOG2(x) __builtin_amdgcn_logf(x)    // v_log_f32 (base-2)

__device__ __forceinline__ float lse2_2(float a, float b) {
    float m = fmaxf(a, b);
    float d = fminf(a, b) - m;
    return m + LOG2(1.0f + EXP2(d));
}
__device__ __forceinline__ float dppf_shr(float x) {  // lane i <- i-1; lane0<-0
    return __int_as_float(__builtin_amdgcn_update_dpp(
        0, __float_as_int(x), 0x138, 0xf, 0xf, false));
}
__device__ __forceinline__ int dppi_shr(int x) {
    return __builtin_amdgcn_update_dpp(0, x, 0x138, 0xf, 0xf, false);
}
__device__ __forceinline__ float dppf_shl(float x) {  // lane i <- i+1; lane63<-0
    return __int_as_float(__builtin_amdgcn_update_dpp(
        0, __float_as_int(x), 0x130, 0xf, 0xf, false));
}
__device__ __forceinline__ int dppi_shl(int x) {
    return __builtin_amdgcn_update_dpp(0, x, 0x130, 0xf, 0xf, false);
}
__device__ __forceinline__ float rdlanef(float x, int i) {
    return __int_as_float(__builtin_amdgcn_readlane(__float_as_int(x), i));
}

__device__ __forceinline__ void stage_rows(const float* gsrc, float* ldst, int lane) {
#pragma unroll
    for (int i = 0; i < CHUNK / 2; ++i) {
        __builtin_amdgcn_global_load_lds(
            (const __attribute__((address_space(1))) void*)(gsrc + i * 256 + lane * 4),
            (__attribute__((address_space(3))) void*)(ldst + i * 256),
            16, 0, 0);
    }
}

// ---------------- fwd producer chunk (r13/r18 proven) ----------------
__device__ __forceinline__ void produce_fwd(const float* __restrict__ rk,
        float* __restrict__ qd, int lane, int label, int t0, int tendF, float& llg)
{
    const float pbv = rk[(lane & 31) * C_ + BLANK_] + EPSF;
    const float rpb = __builtin_amdgcn_rcpf(pbv) * 0.5f;
    const float erb = EPSF * rpb;
    const int t = t0 + lane;
    llg += ((lane < 32) && (t >= 1) && (t < tendF)) ? LOG2(pbv) : 0.0f;
#pragma unroll
    for (int k = 0; k < 8; ++k) {
        float q[4];
#pragma unroll
        for (int j = 0; j < 4; ++j) {
            const int r = 4 * k + j;
            const float pl = rk[r * C_ + label];
            q[j] = fmaf(pl, rdlanef(rpb, r), rdlanef(erb, r));
        }
        *reinterpret_cast<float4*>(qd + lane * QSTRF + 4 * k) =
            make_float4(q[0], q[1], q[2], q[3]);
    }
}

// ---------------- bwd producer chunk: q + pre-shifted ksh -------------
__device__ __forceinline__ void produce_bwd(const float* __restrict__ rk,
        float* __restrict__ qd, int lane, int label, float kf,
        int tLo, int start, float& llg)
{
    const float pbv = rk[(lane & 31) * C_ + BLANK_] + EPSF;
    const float rpb = __builtin_amdgcn_rcpf(pbv) * 0.5f;
    const float erb = EPSF * rpb;
    const int t = start + (lane & 31);
    llg += ((lane < 32) && (t >= tLo)) ? LOG2(pbv) : 0.0f;
    float* base = qd + lane * QSTRB;
#pragma unroll
    for (int k = 0; k < 8; ++k) {
        float q4[4], k4[4];
#pragma unroll
        for (int j = 0; j < 4; ++j) {
            const int r = 4 * k + j;
            const float pl = rk[r * C_ + label];
            const float qv = fmaf(pl, rdlanef(rpb, r), rdlanef(erb, r));
            float ksh = __shfl_down(kf * qv, 1);     // lane l <- l+1
            k4[j] = (lane < 63) ? ksh : 0.0f;
            q4[j] = qv;
        }
        // step j = 31 - r: store reversed so consumer reads j ascending
        *reinterpret_cast<float4*>(base + (28 - 4 * k)) =
            make_float4(q4[3], q4[2], q4[1], q4[0]);
        *reinterpret_cast<float4*>(base + 32 + (28 - 4 * k)) =
            make_float4(k4[3], k4[2], k4[1], k4[0]);
    }
}

// ---------------- fwd consumer step + renorm (r13 proven) -------------
template<bool HAS128>
__device__ __forceinline__ void renorm_f(float& A0, float& A1, float& A2,
        int& e, float& sch, float& kq, float skipf2) {
    float m2 = fmaxf(A0, A1);
    if (HAS128) m2 = fmaxf(m2, A2);
    const bool out = (m2 > 16777216.0f) ||
                     ((m2 < 5.9604644775390625e-8f) && (m2 > 0.0f));
    if (__any(out)) {
        const float mm = (m2 == 0.0f) ? 1.0f : m2;
        const int eb = __float_as_int(mm) >> 23;
        const float s = __int_as_float((254 - eb) << 23);
        A0 *= s; A1 *= s;
        if (HAS128) A2 *= s;
        e += eb - 127;
        int d = dppi_shr(e) - e;
        d = d < -125 ? -125 : (d > 127 ? 127 : d);
        sch = __int_as_float((d + 126) << 23);     // 0.5*2^d
        kq = skipf2 * sch;
    }
}
template<bool HAS128>
__device__ __forceinline__ void step_f(float& A0, float& A1, float& A2,
        float sch, float kq, float ql) {
    const float P1 = dppf_shr(A1) * sch;
    const float A0o = A0, A1o = A1;
    A0 = fmaf(A0o, 0.5f, P1);
    const float t = fmaf(kq, dppf_shr(A1o), A0o);  // kq*s1 (s1 recomputed: CSE'd)
    A1 = (A1o + fmaf(kq, 0.0f, t - A0o + A0o)) * ql; // placeholder-free below
    if (HAS128) A2 = (A2 + A1o) * 0.5f;
}

// NOTE: step_f above is replaced by the exact r13 step inline in the loop
// (kept r13-verbatim there); this stub is unused.

// ---------------- bwd consumer step + renorm --------------------------
template<bool HAS128>
__device__ __forceinline__ void renorm_b(float& b0, float& b1, float& b2,
        int& e, float& schB, float& scfB) {
    float m2 = fmaxf(b0, b1);
    if (HAS128) m2 = fmaxf(m2, b2);
    const bool out = (m2 > 16777216.0f) ||
                     ((m2 < 5.9604644775390625e-8f) && (m2 > 0.0f));
    if (__any(out)) {
        const float mm = (m2 == 0.0f) ? 1.0f : m2;
        const int eb = __float_as_int(mm) >> 23;
        const float s = __int_as_float((254 - eb) << 23);
        b0 *= s; b1 *= s;
        if (HAS128) b2 *= s;
        e += eb - 127;
        int d = dppi_shl(e) - e;
        d = d < -125 ? -125 : (d > 126 ? 126 : d);
        scfB = __int_as_float((d + 127) << 23);    // 2^d
        schB = __int_as_float((d + 126) << 23);    // 0.5*2^d
    }
}
template<bool HAS128>
__device__ __forceinline__ void step_b(float& b0, float& b1, float& b2,
        float schB, float scfB, float h63, float q, float ksh) {
    const float s0 = dppf_shl(b0);
    const float s1 = dppf_shl(b1);
    const float t1 = q * b1;
    const float b0n = fmaf(0.5f, b0, t1);
    float t2 = fmaf(schB, s0, t1);
    if (HAS128) t2 = fmaf(h63, b2, t2);            // pb*beta(128) into beta(127)
    const float b1n = fmaf(scfB, ksh * s1, t2);
    if (HAS128) b2 *= 0.5f;
    b0 = b0n; b1 = b1n;
}

__global__ __launch_bounds__(256) void ctc_fwd_kernel(
    const int* __restrict__ y_true, const float* __restrict__ y_pred,
    const int* __restrict__ input_len, const int* __restrict__ label_len,
    float* __restrict__ out)
{
    __shared__ __align__(16) float rawF[2][CHUNK * C_];    // 32 KB
    __shared__ __align__(16) float rawB[2][CHUNK * C_];    // 32 KB
    __shared__ __align__(16) float qf[2][64 * QSTRF];      // 18.4 KB
    __shared__ __align__(16) float qb[2][64 * QSTRB];      // 34.8 KB
    __shared__ float bstate[4][64];                        // 1 KB
    __shared__ float extra[8];  // [0]A1i [1]A0i [2]lgf [3]lgb

    const int b = blockIdx.x;
    const int tid = threadIdx.x;
    const int lane = tid & 63;
    const int wid = tid >> 6;
    const float* __restrict__ Pg = y_pred + (size_t)b * T_ * C_;
    const int label = y_true[b * L_ + lane];
    const int in_len = input_len[b];
    const int tend = in_len < T_ ? in_len : T_;            // >= 256
    const int m_ = (tend - 1) >> 1;                        // fwd steps 1..m_
    const int tendF = m_ + 1;
    const int mB = tend - 1 - m_;                          // bwd steps
    const int nf = (tendF + CHUNK - 1) / CHUNK;            // 4..8
    const int nb = (mB + CHUNK - 1) / CHUNK;               // <= nf
    const int NI = nf;
    const int lprev = __shfl_up(label, 1);
    const float kf = (lane > 0 && label != lprev) ? 1.0f : 0.0f;
    const int lab = label_len[b];
    const bool has128 = (lab == L_);

    if (wid == 2) {
        // ---------------- fwd producer ----------------
        float llg = 0.0f;
        stage_rows(Pg, rawF[0], lane);
        stage_rows(Pg + CHUNK * C_, rawF[1], lane);
        asm volatile("s_waitcnt vmcnt(16)" ::: "memory");
        produce_fwd(rawF[0], qf[0], lane, label, 0, tendF, llg);
        if (lane == 0) {
            extra[0] = rawF[0][label]  + EPSF;             // A1 init (s=1)
            extra[1] = rawF[0][BLANK_] + EPSF;             // A0 init (s=0)
        }
        asm volatile("s_waitcnt lgkmcnt(0)" ::: "memory");
        __builtin_amdgcn_s_barrier();                      // B0
        for (int i = 0; i < NI; ++i) {
            if (i + 2 < nf)
                stage_rows(Pg + (size_t)(i + 2) * CHUNK * C_, rawF[i & 1], lane);
            if (i + 1 < nf) {
                if (i + 2 < nf) asm volatile("s_waitcnt vmcnt(16)" ::: "memory");
                else            asm volatile("s_waitcnt vmcnt(0)" ::: "memory");
                produce_fwd(rawF[(i + 1) & 1], qf[(i + 1) & 1], lane, label,
                            (i + 1) * CHUNK, tendF, llg);
                asm volatile("s_waitcnt lgkmcnt(0)" ::: "memory");
            }
            __builtin_amdgcn_s_barrier();
        }
#pragma unroll
        for (int off = 16; off >= 1; off >>= 1) llg += __shfl_xor(llg, off);
        if (lane == 0) extra[2] = llg;
        asm volatile("s_waitcnt lgkmcnt(0)" ::: "memory");
        __builtin_amdgcn_s_barrier();                      // BF
    } else if (wid == 3) {
        // ---------------- bwd producer ----------------
        float llg = 0.0f;
        stage_rows(Pg + (size_t)(tend - CHUNK) * C_, rawB[0], lane);
        stage_rows(Pg + (size_t)(tend - 2 * CHUNK) * C_, rawB[1], lane);
        asm volatile("s_waitcnt vmcnt(16)" ::: "memory");
        produce_bwd(rawB[0], qb[0], lane, label, kf, tendF, tend - CHUNK, llg);
        asm volatile("s_waitcnt lgkmcnt(0)" ::: "memory");
        __builtin_amdgcn_s_barrier();                      // B0
        for (int i = 0; i < NI; ++i) {
            if (i + 2 < nb)
                stage_rows(Pg + (size_t)(tend - (i + 3) * CHUNK) * C_,
                           rawB[i & 1], lane);
            if (i + 1 < nb) {
                if (i + 2 < nb) asm volatile("s_waitcnt vmcnt(16)" ::: "memory");
                else            asm volatile("s_waitcnt vmcnt(0)" ::: "memory");
                produce_bwd(rawB[(i + 1) & 1], qb[(i + 1) & 1], lane, label, kf,
                            tendF, tend - (i + 2) * CHUNK, llg);
                asm volatile("s_waitcnt lgkmcnt(0)" ::: "memory");
            }
            __builtin_amdgcn_s_barrier();
        }
#pragma unroll
        for (int off = 16; off >= 1; off >>= 1) llg += __shfl_xor(llg, off);
        if (lane == 0) extra[3] = llg;
        asm volatile("s_waitcnt lgkmcnt(0)" ::: "memory");
        __builtin_amdgcn_s_barrier();                      // BF
    } else if (wid == 1) {
        // ---------------- bwd consumer ----------------
        const float h63 = (lane == 63) ? 0.5f : 0.0f;
        float b0 = (!has128 && lane == lab) ? 1.0f : 0.0f;
        float b1 = (lane == lab - 1) ? 1.0f : 0.0f;
        float b2 = (has128 && lane == 63) ? 1.0f : 0.0f;
        float schB = 0.5f, scfB = 1.0f;
        int e = 0;
        __builtin_amdgcn_s_barrier();                      // B0
        for (int d = 0; d < NI; ++d) {
            if (d < nb) {
                const float* qp = &qb[d & 1][lane * QSTRB];
                float q[CHUNK], ks[CHUNK];
#pragma unroll
                for (int k = 0; k < 8; ++k) {
                    const float4 t4 = *reinterpret_cast<const float4*>(qp + 4 * k);
                    q[4*k+0] = t4.x; q[4*k+1] = t4.y; q[4*k+2] = t4.z; q[4*k+3] = t4.w;
                }
#pragma unroll
                for (int k = 0; k < 8; ++k) {
                    const float4 t4 = *reinterpret_cast<const float4*>(qp + 32 + 4 * k);
                    ks[4*k+0] = t4.x; ks[4*k+1] = t4.y; ks[4*k+2] = t4.z; ks[4*k+3] = t4.w;
                }
                asm volatile("s_waitcnt lgkmcnt(0)" ::: "memory");
                __builtin_amdgcn_s_barrier();
                __builtin_amdgcn_sched_barrier(0);
                const int len = mB - d * CHUNK;
                if (has128) {
                    if (len >= CHUNK) {
#pragma unroll
                        for (int u = 0; u < CHUNK; ++u) {
                            step_b<true>(b0, b1, b2, schB, scfB, h63, q[u], ks[u]);
                            if ((u & 3) == 3) renorm_b<true>(b0, b1, b2, e, schB, scfB);
                        }
                    } else {
#pragma unroll
                        for (int u = 0; u < CHUNK; ++u) {
                            const float o0 = b0, o1 = b1, o2 = b2;
                            step_b<true>(b0, b1, b2, schB, scfB, h63, q[u], ks[u]);
                            const bool v = u < len;
                            b0 = v ? b0 : o0; b1 = v ? b1 : o1; b2 = v ? b2 : o2;
                            if ((u & 3) == 3) renorm_b<true>(b0, b1, b2, e, schB, scfB);
                        }
                    }
                } else {
                    if (len >= CHUNK) {
#pragma unroll
                        for (int u = 0; u < CHUNK; ++u) {
                            step_b<false>(b0, b1, b2, schB, scfB, h63, q[u], ks[u]);
                            if ((u & 3) == 3) renorm_b<false>(b0, b1, b2, e, schB, scfB);
                        }
                    } else {
#pragma unroll
                        for (int u = 0; u < CHUNK; ++u) {
                            const float o0 = b0, o1 = b1;
                            step_b<false>(b0, b1, b2, schB, scfB, h63, q[u], ks[u]);
                            const bool v = u < len;
                            b0 = v ? b0 : o0; b1 = v ? b1 : o1;
                            if ((u & 3) == 3) renorm_b<false>(b0, b1, b2, e, schB, scfB);
                        }
                    }
                }
            } else {
                __builtin_amdgcn_s_barrier();
            }
        }
        bstate[0][lane] = b0;
        bstate[1][lane] = b1;
        bstate[2][lane] = b2;
        bstate[3][lane] = (float)e;
        asm volatile("s_waitcnt lgkmcnt(0)" ::: "memory");
        __builtin_amdgcn_s_barrier();                      // BF
    } else {
        // ---------------- fwd consumer + merge ----------------
        const float skipf2 = 2.0f * kf;
        float A0 = 0.0f, A1 = 0.0f, A2 = 0.0f;
        float sch = 0.5f, kq = skipf2 * 0.5f;
        int e = 0;
        __builtin_amdgcn_s_barrier();                      // B0
        for (int c = 0; c < NI; ++c) {
            const float* qp = &qf[c & 1][lane * QSTRF];
            float q[CHUNK];
#pragma unroll
            for (int k = 0; k < 8; ++k) {
                const float4 t4 = *reinterpret_cast<const float4*>(qp + 4 * k);
                q[4*k+0] = t4.x; q[4*k+1] = t4.y; q[4*k+2] = t4.z; q[4*k+3] = t4.w;
            }
            asm volatile("s_waitcnt lgkmcnt(0)" ::: "memory");
            __builtin_amdgcn_s_barrier();
            __builtin_amdgcn_sched_barrier(0);
            const int rem = tendF - c * CHUNK;
            const int u0 = (c == 0) ? 1 : 0;
            if (c == 0) {
                A0 = (lane == 0) ? extra[1] : 0.0f;
                A1 = (lane == 0) ? extra[0] : 0.0f;
            }
            if (has128) {
                if (rem >= CHUNK) {
#pragma unroll
                    for (int u = 0; u < CHUNK; ++u) {
                        if (u >= u0) {
                            const float P1 = dppf_shr(A1) * sch;
                            const float A0o = A0, A1o = A1;
                            A0 = fmaf(A0o, 0.5f, P1);
                            const float t = fmaf(skipf2, P1, A0o);
                            A1 = (A1o + t) * q[u];
                            A2 = (A2 + A1o) * 0.5f;
                        }
                        if ((u & 3) == 3) renorm_f<true>(A0, A1, A2, e, sch, kq, skipf2);
                    }
                } else {
#pragma unroll
                    for (int u = 0; u < CHUNK; ++u) {
                        const float o0 = A0, o1 = A1, o2 = A2;
                        const float P1 = dppf_shr(A1) * sch;
                        A0 = fmaf(o0, 0.5f, P1);
                        const float t = fmaf(skipf2, P1, o0);
                        A1 = (o1 + t) * q[u];
                        A2 = (A2 + o1) * 0.5f;
                        const bool v = u < rem;
                        A0 = v ? A0 : o0; A1 = v ? A1 : o1; A2 = v ? A2 : o2;
                        if ((u & 3) == 3) renorm_f<true>(A0, A1, A2, e, sch, kq, skipf2);
                    }
                }
            } else {
                if (rem >= CHUNK) {
#pragma unroll
                    for (int u = 0; u < CHUNK; ++u) {
                        if (u >= u0) {
                            const float P1 = dppf_shr(A1) * sch;
                            const float A0o = A0, A1o = A1;
                            A0 = fmaf(A0o, 0.5f, P1);
                            const float t = fmaf(skipf2, P1, A0o);
                            A1 = (A1o + t) * q[u];
                        }
                        if ((u & 3) == 3) renorm_f<false>(A0, A1, A2, e, sch, kq, skipf2);
                    }
                } else {
#pragma unroll
                    for (int u = 0; u < CHUNK; ++u) {
                        const float o0 = A0, o1 = A1;
                        const float P1 = dppf_shr(A1) * sch;
                        A0 = fmaf(o0, 0.5f, P1);
                        const float t = fmaf(skipf2, P1, o0);
                        A1 = (o1 + t) * q[u];
                        const bool v = u < rem;
                        A0 = v ? A0 : o0; A1 = v ? A1 : o1;
                        if ((u & 3) == 3) renorm_f<false>(A0, A1, A2, e, sch, kq, skipf2);
                    }
                }
            }
        }
        __builtin_amdgcn_s_barrier();                      // BF
        // ------------- merge: sum_s alpha_m(s)*beta_m(s) -------------
        const float B0v = bstate[0][lane];
        const float B1v = bstate[1][lane];
        const float B2v = bstate[2][lane];
        const float es  = (float)e + bstate[3][lane];
        float l0 = LOG2(A0) + LOG2(B0v) + es;
        float l1 = LOG2(A1) + LOG2(B1v) + es;
        l0 = fmaxf(l0, NEGF);                              // kill -inf (NaN guard)
        l1 = fmaxf(l1, NEGF);
        float v = lse2_2(l0, l1);
        if (has128) {
            float l2 = LOG2(A2) + LOG2(B2v) + es;
            l2 = (lane == 63) ? fmaxf(l2, NEGF) : NEGF;
            v = lse2_2(v, l2);
        }
#pragma unroll
        for (int off = 32; off >= 1; off >>= 1)
            v = lse2_2(v, __shfl_xor(v, off));
        if (lane == 0)
            out[b] = -LN2F * (v + extra[2] + extra[3] + (float)(tend - 1));
    }
}

extern "C" void kernel_launch(void* const* d_in, const int* in_sizes, int n_in,
                              void* d_out, int out_size, void* d_ws, size_t ws_size,
                              hipStream_t stream) {
    const int*   y_true    = (const int*)d_in[0];
    const float* y_pred    = (const float*)d_in[1];
    const int*   input_len = (const int*)d_in[2];
    const int*   label_len = (const int*)d_in[3];
    float* out = (float*)d_out;

    ctc_fwd_kernel<<<B_, 256, 0, stream>>>(y_true, y_pred, input_len, label_len, out);
}

// Round 22
// 23.479 us; speedup vs baseline: 1.3914x; 1.0293x over previous
//
#include <hip/hip_runtime.h>

// CTC batch cost (Keras ctc_batch_cost), B=256, T=512, C=128, L=64.
// 256 blocks x 128 threads, NO producer waves, ONE barrier total:
//   wave0 = forward alpha over rows 0..m   (m = (tend-2)/2), then merge
//   wave1 = backward beta over rows tend-1..m+1
// Each wave is the proven r9 self-contained structure: global_load_lds
// double-buffered staging (counted vmcnt), raw-prob linear domain with
// per-lane pow2 exponent, fat (dead-lane exponent adoption) then lean.
// Range: every p+eps is folded as fmaf(p,128,1.28e-5) (= 128*(p+1e-7),
// one fma, exact 2^7 scale) -> exponent drift ~0; total scale 2^(7*tend)
// subtracted at the end. Backward recurrence (state s=2l blank / 2l+1=y_l):
//   b0' = pb*(b0+b1);  b1' = pl*(b1 + scf*shl(b0 + kf*b1) [+ s2m*b2m @63])
// with (b2m,e2) = wave-uniform state-128 track (lab==64 only).
// Merge: loss = -log sum_s alpha_m(s)*B(s), B = transition-only closure of
// beta_{m+1}; per-lane log2 + 6-level lse shuffle reduce.

#define B_ 256
#define T_ 512
#define C_ 128
#define L_ 64
#define BLANK_ 127
#define CHUNK 32
#define SC128 128.0f
#define EPS128 1.28e-5f          // 128 * 1e-7
#define LN2F 0.6931471805599453f
#define NEGF (-1e30f)

#define EXP2(x) __builtin_amdgcn_exp2f(x)   // v_exp_f32 (base-2)
#define LOG2(x) __builtin_amdgcn_logf(x)    // v_log_f32 (base-2)

__device__ __forceinline__ float lse2_2(float a, float b) {
    float m = fmaxf(a, b);
    float d = fminf(a, b) - m;
    return m + LOG2(1.0f + EXP2(d));
}
__device__ __forceinline__ float dppf_shr(float x) {  // lane i <- i-1; lane0<-0
    return __int_as_float(__builtin_amdgcn_update_dpp(
        0, __float_as_int(x), 0x138, 0xf, 0xf, false));
}
__device__ __forceinline__ int dppi_shr(int x) {
    return __builtin_amdgcn_update_dpp(0, x, 0x138, 0xf, 0xf, false);
}
__device__ __forceinline__ float dppf_shl(float x) {  // lane i <- i+1; lane63<-0
    return __int_as_float(__builtin_amdgcn_update_dpp(
        0, __float_as_int(x), 0x130, 0xf, 0xf, false));
}
__device__ __forceinline__ int dppi_shl(int x) {
    return __builtin_amdgcn_update_dpp(0, x, 0x130, 0xf, 0xf, false);
}
__device__ __forceinline__ float rdlanef(float x, int i) {
    return __int_as_float(__builtin_amdgcn_readlane(__float_as_int(x), i));
}
__device__ __forceinline__ float delta2(int d) {      // exact 2^clamp(d,+-126)
    d = d < -126 ? -126 : (d > 126 ? 126 : d);
    return __int_as_float((d + 127) << 23);
}
__device__ __forceinline__ int extract_ex(float m) {  // 0 unless normal finite
    const int mb = __float_as_int(m);
    const bool valid = (unsigned)(mb - 0x00800000) < 0x7f000000u;
    return valid ? (mb >> 23) - 127 : 0;
}

__device__ __forceinline__ void stage_chunk(const float* gsrc, float* ldst, int lane) {
#pragma unroll
    for (int i = 0; i < CHUNK / 2; ++i)
        __builtin_amdgcn_global_load_lds(
            (const __attribute__((address_space(1))) void*)(gsrc + i * 256 + lane * 4),
            (__attribute__((address_space(3))) void*)(ldst + i * 256), 16, 0, 0);
}

// ============================ forward (r9) ============================
template<bool H128>
__device__ __forceinline__ void renormF(float& A0, float& A1, float& A2, int& e) {
    float m = fmaxf(A0, A1);
    if (H128) m = fmaxf(m, A2);
    const int ex = extract_ex(m);
    const float s = __int_as_float((127 - ex) << 23);
    A0 *= s; A1 *= s;
    if (H128) A2 *= s;
    e += ex;
}

template<bool H128, bool FULL>
__device__ __forceinline__ void fgroup(const float* __restrict__ Lb, int base,
        int label, float skipf, float pbv, int lo, int hi,
        float& A0, float& A1, float& A2, int& e)
{
    float pl[16];
#pragma unroll
    for (int u = 0; u < 16; ++u) pl[u] = Lb[(base + u) * C_ + label];
#pragma unroll
    for (int u = 0; u < 16; ++u) pl[u] = fmaf(pl[u], SC128, EPS128);
#pragma unroll
    for (int u = 0; u < 16; ++u) {
        const int r = base + u;
        const float pb = rdlanef(pbv, r);
        const float p1 = dppf_shr(A1);
        const int   ep = dppi_shr(e);
        const bool dead = (fmaxf(A0, A1) == 0.0f);
        const int   e1 = dead ? ep : e;
        const float sc = delta2(ep - e1);
        const float P1 = p1 * sc;
        const float A0o = A0, A1o = A1;
        const float nA0 = (A0o + P1) * pb;
        const float t   = fmaf(skipf, P1, A0o);
        const float nA1 = (A1o + t) * pl[u];
        const float nA2 = H128 ? (A2 + A1o) * pb : A2;
        if (FULL) {
            A0 = nA0; A1 = nA1; e = e1;
            if (H128) A2 = nA2;
        } else {
            const bool v = (r >= lo) & (r < hi);
            A0 = v ? nA0 : A0o; A1 = v ? nA1 : A1o; e = v ? e1 : e;
            if (H128) A2 = v ? nA2 : A2;
        }
        if ((u & 3) == 3) renormF<H128>(A0, A1, A2, e);
    }
}

template<bool H128, bool GUARD>
__device__ __forceinline__ void fgroupL(const float* __restrict__ Lb, int base,
        int label, float skipf, float pbv, int hi,
        float& A0, float& A1, float& A2, int& e, float& sc)
{
    float pl[16];
#pragma unroll
    for (int u = 0; u < 16; ++u) pl[u] = Lb[(base + u) * C_ + label];
#pragma unroll
    for (int u = 0; u < 16; ++u) pl[u] = fmaf(pl[u], SC128, EPS128);
#pragma unroll
    for (int u = 0; u < 16; ++u) {
        const int r = base + u;
        const float pb = rdlanef(pbv, r);
        const float P1 = dppf_shr(A1) * sc;
        const float A0o = A0, A1o = A1;
        const float nA0 = (A0o + P1) * pb;
        const float t   = fmaf(skipf, P1, A0o);
        const float nA1 = (A1o + t) * pl[u];
        const float nA2 = H128 ? (A2 + A1o) * pb : A2;
        if (GUARD) {
            const bool v = r < hi;
            A0 = v ? nA0 : A0o; A1 = v ? nA1 : A1o;
            if (H128) A2 = v ? nA2 : A2;
        } else { A0 = nA0; A1 = nA1; if (H128) A2 = nA2; }
        if ((u & 3) == 3) { renormF<H128>(A0, A1, A2, e); sc = delta2(dppi_shr(e) - e); }
    }
}

template<bool H128>
__device__ void fwd_run(const float* __restrict__ Pg, float (*lds)[CHUNK * C_],
        int label, float skipf, int tendF, int lane,
        float& A0, float& A1, float& A2, int& e)
{
    const int nch = (tendF + 31) / 32;                 // 4..8
    stage_chunk(Pg, lds[0], lane);
    stage_chunk(Pg + CHUNK * C_, lds[1], lane);
    float sc = 1.0f;
    for (int c = 0; c < nch; ++c) {
        if (c + 1 < nch) asm volatile("s_waitcnt vmcnt(16)" ::: "memory");
        else             asm volatile("s_waitcnt vmcnt(0)" ::: "memory");
        const float* Lb = lds[c & 1];
        const float pbv = fmaf(Lb[(lane & 31) * C_ + BLANK_], SC128, EPS128);
        const int rem = tendF - c * CHUNK;
        if (c == 0) {
            A0 = (lane == 0) ? fmaf(Lb[BLANK_], SC128, EPS128) : 0.0f;
            A1 = (lane == 0) ? fmaf(Lb[label], SC128, EPS128) : 0.0f;
            fgroup<H128, false>(Lb, 0, label, skipf, pbv, 1, 16, A0, A1, A2, e);
            fgroup<H128, true >(Lb, 16, label, skipf, pbv, 0, 0, A0, A1, A2, e);
        } else if (c < 4) {
            fgroup<H128, true>(Lb, 0, label, skipf, pbv, 0, 0, A0, A1, A2, e);
            fgroup<H128, true>(Lb, 16, label, skipf, pbv, 0, 0, A0, A1, A2, e);
        } else {
            if (c == 4) sc = delta2(dppi_shr(e) - e);
            if (rem >= CHUNK) {
                fgroupL<H128, false>(Lb, 0, label, skipf, pbv, 32, A0, A1, A2, e, sc);
                fgroupL<H128, false>(Lb, 16, label, skipf, pbv, 32, A0, A1, A2, e, sc);
            } else if (rem > 16) {
                fgroupL<H128, false>(Lb, 0, label, skipf, pbv, 32, A0, A1, A2, e, sc);
                fgroupL<H128, true >(Lb, 16, label, skipf, pbv, rem, A0, A1, A2, e, sc);
            } else {
                fgroupL<H128, true>(Lb, 0, label, skipf, pbv, rem, A0, A1, A2, e, sc);
            }
        }
        if (c + 2 < nch)
            stage_chunk(Pg + (size_t)(c + 2) * CHUNK * C_, lds[c & 1], lane);
    }
}

// ============================ backward ============================
// step (row r): b0' = pb*(b0+b1); b1' = pl*(b1 + scl*shl(b0+kf*b1) [+s2m*b2m])
template<bool H128, bool FAT, bool GUARD>
__device__ __forceinline__ void bgroup(const float* __restrict__ Lb, int R0,
        int label, float kf, float pbv, int hi,
        float& b0, float& b1, float& b2m, int& e, int& e2,
        float& scf, float& s2m, int lane)
{
    float pl[16];
#pragma unroll
    for (int u = 0; u < 16; ++u) pl[u] = Lb[((R0 - u) & 31) * C_ + label];
#pragma unroll
    for (int u = 0; u < 16; ++u) pl[u] = fmaf(pl[u], SC128, EPS128);
#pragma unroll
    for (int u = 0; u < 16; ++u) {
        const float pb = rdlanef(pbv, (R0 - u) & 31);
        const float w  = fmaf(kf, b1, b0);
        const float sw = dppf_shl(w);
        float scl = scf;
        int e1 = e;
        if (FAT) {
            const int ep = dppi_shl(e);
            const bool dead = (fmaxf(b0, b1) == 0.0f);
            e1 = dead ? ep : e;
            scl = delta2(ep - e1);
        }
        const float b0o = b0, b1o = b1;
        float t = fmaf(scl, sw, b1o);
        if (H128) t = fmaf(s2m, b2m, t);
        const float nb1 = pl[u] * t;
        const float nb0 = (b0o + b1o) * pb;
        if (GUARD) {
            const bool v = u < hi;
            b0 = v ? nb0 : b0o; b1 = v ? nb1 : b1o;
            if (FAT) e = v ? e1 : e;
            if (H128) b2m = v ? (b2m * pb) : b2m;
        } else {
            b0 = nb0; b1 = nb1;
            if (FAT) e = e1;
            if (H128) b2m = b2m * pb;
        }
        if ((u & 3) == 3) {
            const float m = fmaxf(b0, b1);
            const int ex = extract_ex(m);
            const float s = __int_as_float((127 - ex) << 23);
            b0 *= s; b1 *= s; e += ex;
            if (!FAT) scf = delta2(dppi_shl(e) - e);
            if (H128) {
                const int ex2 = extract_ex(b2m);
                b2m *= __int_as_float((127 - ex2) << 23);
                e2 += ex2;
                s2m = (lane == 63) ? delta2(e2 - e) : 0.0f;
            }
        }
    }
}

template<bool H128>
__device__ void bwd_run(const float* __restrict__ Pg, float (*lds)[CHUNK * C_],
        int label, float kf, int lab, int tend, int m_, int lane,
        float& b0, float& b1, float& b2m, int& e, int& e2,
        float& scf, float& s2m)
{
    const int sbwd = tend - 2 - m_;                    // steps (>=127)
    const int nch = (tend - m_ + 30) / 32;             // ceil((tend-1-m_)/32)
    stage_chunk(Pg + (size_t)(tend - CHUNK) * C_, lds[0], lane);
    stage_chunk(Pg + (size_t)(tend - 2 * CHUNK) * C_, lds[1], lane);
    for (int c = 0; c < nch; ++c) {
        if (c + 1 < nch) asm volatile("s_waitcnt vmcnt(16)" ::: "memory");
        else             asm volatile("s_waitcnt vmcnt(0)" ::: "memory");
        const float* Lb = lds[c & 1];
        const float pbv = fmaf(Lb[(lane & 31) * C_ + BLANK_], SC128, EPS128);
        if (c == 0) {
            // init absorbs row tend-1 (local 31)
            const float pb31 = rdlanef(pbv, 31);
            const float plv = fmaf(Lb[31 * C_ + label], SC128, EPS128);
            b1 = (lane == lab - 1) ? plv : 0.0f;
            b0 = (!H128 && lane == lab) ? pb31 : 0.0f;
            if (H128) b2m = pb31;
            bgroup<H128, true, false>(Lb, 30, label, kf, pbv, 16, b0, b1, b2m, e, e2, scf, s2m, lane);
            bgroup<H128, true, true >(Lb, 14, label, kf, pbv, 15, b0, b1, b2m, e, e2, scf, s2m, lane);
        } else {
            const int remk = sbwd - (32 * c - 1);      // steps left from chunk start
            if (c < 4) {                               // remk >= 32 (sbwd >= 127)
                bgroup<H128, true, false>(Lb, 31, label, kf, pbv, 16, b0, b1, b2m, e, e2, scf, s2m, lane);
                bgroup<H128, true, false>(Lb, 15, label, kf, pbv, 16, b0, b1, b2m, e, e2, scf, s2m, lane);
            } else {
                if (c == 4) {
                    scf = delta2(dppi_shl(e) - e);
                    if (H128) s2m = (lane == 63) ? delta2(e2 - e) : 0.0f;
                }
                if (remk >= 32) {
                    bgroup<H128, false, false>(Lb, 31, label, kf, pbv, 16, b0, b1, b2m, e, e2, scf, s2m, lane);
                    bgroup<H128, false, false>(Lb, 15, label, kf, pbv, 16, b0, b1, b2m, e, e2, scf, s2m, lane);
                } else if (remk > 16) {
                    bgroup<H128, false, false>(Lb, 31, label, kf, pbv, 16, b0, b1, b2m, e, e2, scf, s2m, lane);
                    bgroup<H128, false, true >(Lb, 15, label, kf, pbv, remk - 16, b0, b1, b2m, e, e2, scf, s2m, lane);
                } else {
                    bgroup<H128, false, true>(Lb, 31, label, kf, pbv, remk, b0, b1, b2m, e, e2, scf, s2m, lane);
                }
            }
        }
        if (c + 2 < nch)
            stage_chunk(Pg + (size_t)(tend - (c + 3) * CHUNK) * C_, lds[c & 1], lane);
    }
    // fresh alignment scales for the transition-only closure
    scf = delta2(dppi_shl(e) - e);
    if (H128) s2m = (lane == 63) ? delta2(e2 - e) : 0.0f;
}

// ============================ kernel ============================
__global__ __launch_bounds__(128) void ctc_fwd_kernel(
    const int* __restrict__ y_true, const float* __restrict__ y_pred,
    const int* __restrict__ input_len, const int* __restrict__ label_len,
    float* __restrict__ out)
{
    __shared__ __align__(16) float ldsF[2][CHUNK * C_];   // 32 KB
    __shared__ __align__(16) float ldsB[2][CHUNK * C_];   // 32 KB
    __shared__ float bst0[64], bst1[64], bste[64], bst2[2];

    const int b = blockIdx.x;
    const int tid = threadIdx.x;
    const int lane = tid & 63;
    const float* __restrict__ Pg = y_pred + (size_t)b * T_ * C_;
    const int label = y_true[b * L_ + lane];
    const int in_len = input_len[b];
    const int lab = label_len[b];
    const int tend = in_len < T_ ? in_len : T_;           // >= 256
    const int m_ = (tend - 2) >> 1;                       // fwd rows 0..m_
    const bool h128 = (lab == L_);
    const int lprev = __shfl_up(label, 1);
    const float kf = (lane > 0 && label != lprev) ? 1.0f : 0.0f;

    if (tid < 64) {
        // ------------- forward wave + merge -------------
        float A0 = 0.0f, A1 = 0.0f, A2 = 0.0f;
        int e = 0;
        if (h128) fwd_run<true >(Pg, ldsF, label, kf, m_ + 1, lane, A0, A1, A2, e);
        else      fwd_run<false>(Pg, ldsF, label, kf, m_ + 1, lane, A0, A1, A2, e);
        __builtin_amdgcn_s_barrier();                     // beta state ready
        const float B0 = bst0[lane], B1 = bst1[lane], ebf = bste[lane];
        const float S = fmaf(A1, B1, A0 * B0);
        float v = LOG2(S) + (float)e + ebf;
        v = fmaxf(v, NEGF);
        if (h128) {
            float l2 = NEGF;
            if (lane == 63) l2 = LOG2(A2) + LOG2(bst2[0]) + (float)e + bst2[1];
            v = lse2_2(v, fmaxf(l2, NEGF));
        }
#pragma unroll
        for (int off = 32; off >= 1; off >>= 1)
            v = lse2_2(v, __shfl_xor(v, off));
        if (lane == 0) out[b] = LN2F * (7.0f * (float)tend - v);
    } else {
        // ------------- backward wave -------------
        float b0 = 0.0f, b1 = 0.0f, b2m = 1.0f;
        int e = 0, e2 = 0;
        float scf = 1.0f, s2m = (lane == 63) ? 1.0f : 0.0f;
        if (h128) bwd_run<true >(Pg, ldsB, label, kf, lab, tend, m_, lane, b0, b1, b2m, e, e2, scf, s2m);
        else      bwd_run<false>(Pg, ldsB, label, kf, lab, tend, m_, lane, b0, b1, b2m, e, e2, scf, s2m);
        // transition-only closure: B(s) = sum_{s'} allowed(s->s') beta(s')
        const float w = fmaf(kf, b1, b0);
        const float sw = dppf_shl(w);
        float B1 = fmaf(scf, sw, b1);
        if (h128) B1 = fmaf(s2m, b2m, B1);
        bst0[lane] = b0 + b1;                             // B for s=2l
        bst1[lane] = B1;                                  // B for s=2l+1
        bste[lane] = (float)e;
        if (h128 && lane == 63) { bst2[0] = b2m; bst2[1] = (float)e2; }
        asm volatile("s_waitcnt lgkmcnt(0)" ::: "memory");
        __builtin_amdgcn_s_barrier();
    }
}

extern "C" void kernel_launch(void* const* d_in, const int* in_sizes, int n_in,
                              void* d_out, int out_size, void* d_ws, size_t ws_size,
                              hipStream_t stream) {
    const int*   y_true    = (const int*)d_in[0];
    const float* y_pred    = (const float*)d_in[1];
    const int*   input_len = (const int*)d_in[2];
    const int*   label_len = (const int*)d_in[3];
    float* out = (float*)d_out;

    ctc_fwd_kernel<<<B_, 128, 0, stream>>>(y_true, y_pred, input_len, label_len, out);
}